// Round 2
// baseline (156.515 us; speedup 1.0000x reference)
//
#include <hip/hip_runtime.h>
#include <hip/hip_bf16.h>

typedef __bf16 bf16x8 __attribute__((ext_vector_type(8)));
typedef float  f32x4  __attribute__((ext_vector_type(4)));
typedef unsigned short u16x8 __attribute__((ext_vector_type(8)));

#define MFMA16(a,b,c) __builtin_amdgcn_mfma_f32_16x16x32_bf16((a),(b),(c),0,0,0)

__device__ __forceinline__ unsigned short f2bf(float f){
  unsigned int u = __float_as_uint(f);
  u += 0x7fffu + ((u >> 16) & 1u);
  return (unsigned short)(u >> 16);
}

constexpr float SCALE_LOG2E = 0.125f * 1.4426950408889634f; // 1/sqrt(64) * log2(e)

// ---------------- merged prep kernel ----------------
// blocks 0..31: qs+Aq ; blocks 32..287: Cmat+cvec ; blocks 288..543: starts scan
__global__ void k_prep(const float* __restrict__ queries, const float* __restrict__ ipw,
                       const float* __restrict__ ipb, const float* __restrict__ opw,
                       const float* __restrict__ opb, const int* __restrict__ batch,
                       int total, int* __restrict__ starts,
                       unsigned short* __restrict__ Aq,
                       unsigned short* __restrict__ Cmat, float* __restrict__ cvec)
{
  __shared__ __align__(16) float sh[256];
  __shared__ __align__(16) float sh2[256];
  const int t = threadIdx.x, bid = blockIdx.x;

  if (bid < 32){
    // --- qs row q then Aq rows h*32+q ---
    const int q = bid;
    sh[t] = queries[q*256 + t];
    __syncthreads();
    const float* wr = ipw + (size_t)t*256;
    float acc = 0.f;
    #pragma unroll 8
    for (int j = 0; j < 256; j += 4){
      float4 wv = *reinterpret_cast<const float4*>(wr + j);
      float4 qv = *reinterpret_cast<const float4*>(&sh[j]);
      acc += wv.x*qv.x + wv.y*qv.y + wv.z*qv.z + wv.w*qv.w;
    }
    sh2[t] = acc + ipb[t];
    __syncthreads();
    #pragma unroll
    for (int h = 0; h < 4; h++){
      const float* wk = ipw + (size_t)(256 + h*64)*256 + t;
      float a2 = 0.f;
      #pragma unroll 8
      for (int d = 0; d < 64; d++) a2 += sh2[h*64 + d] * wk[(size_t)d*256];
      Aq[(size_t)(h*32 + q)*256 + t] = f2bf(a2 * SCALE_LOG2E);
    }
  } else if (bid < 288){
    // --- Cmat row g + cvec[g] ---
    const int g = bid - 32;
    sh[t] = opw[(size_t)g*256 + t];
    __syncthreads();
    #pragma unroll
    for (int h = 0; h < 4; h++){
      const float* wv = ipw + (size_t)(512 + h*64)*256 + t;
      float acc = 0.f;
      #pragma unroll 8
      for (int d = 0; d < 64; d++) acc += wv[(size_t)d*256] * sh[h*64 + d];
      Cmat[(size_t)g*1024 + h*256 + t] = f2bf(acc);
    }
    sh2[t] = ipb[512 + t] * sh[t];
    __syncthreads();
    for (int off = 128; off > 0; off >>= 1){
      if (t < off) sh2[t] += sh2[t + off];
      __syncthreads();
    }
    if (t == 0) cvec[g] = sh2[0] + opb[g];
  } else {
    // --- parallel boundary scan: starts[b] = first index with batch==b ---
    const int sb = bid - 288;
    const int i0 = sb*1024 + t*4;
    if (i0 + 3 < total){
      if (i0 == 0) starts[0] = 0;
      const int4 b4 = *reinterpret_cast<const int4*>(batch + i0);
      if (b4.y != b4.x) starts[b4.y] = i0 + 1;
      if (b4.z != b4.y) starts[b4.z] = i0 + 2;
      if (b4.w != b4.z) starts[b4.w] = i0 + 3;
      if (i0 + 4 < total){
        const int nxt = batch[i0 + 4];
        if (nxt != b4.w) starts[nxt] = i0 + 4;
      } else {
        starts[128] = total;
      }
    }
  }
}

// ---------------- fused flash attention over raw x ----------------
// grid 256 = graph*2 splits, 512 threads (8 waves, wave = (head, q-half): 16 rows)

#define LOADC(dst, c_) { \
  const int c0_ = (c_)*32; \
  _Pragma("unroll") \
  for (int k = 0; k < 4; k++){ \
    const int node_ = (tid >> 6) + 8*k; \
    const int nl_ = c0_ + node_; \
    float4 v_ = make_float4(0.f,0.f,0.f,0.f); \
    if (nl_ < cnt) v_ = *reinterpret_cast<const float4*>(xg + (size_t)nl_*256 + (tid & 63)*4); \
    dst[k] = v_; } }

#define STAGE(buf, src) { \
  _Pragma("unroll") \
  for (int k = 0; k < 4; k++){ \
    const int node_ = (tid >> 6) + 8*k; \
    const unsigned short b0_ = f2bf(src[k].x), b1_ = f2bf(src[k].y); \
    const unsigned short b2_ = f2bf(src[k].z), b3_ = f2bf(src[k].w); \
    *reinterpret_cast<ushort4*>(&(buf)[node_*264 + (tid & 63)*4]) = make_ushort4(b0_,b1_,b2_,b3_); } }

// transpose xsub[node][f] -> xT[f][node] (pad 40), conflict-free both sides
#define BUILDT(xt, xs) { \
  const int fp_ = (tid & 127)*2, ng_ = tid >> 7; \
  unsigned int w_[8]; \
  _Pragma("unroll") \
  for (int r = 0; r < 8; r++) w_[r] = *reinterpret_cast<const unsigned int*>(&(xs)[(ng_*8 + r)*264 + fp_]); \
  u16x8 lo_, hi_; \
  _Pragma("unroll") \
  for (int r = 0; r < 8; r++){ lo_[r] = (unsigned short)(w_[r] & 0xffffu); hi_[r] = (unsigned short)(w_[r] >> 16); } \
  *reinterpret_cast<u16x8*>(&(xt)[fp_*40 + ng_*8])       = lo_; \
  *reinterpret_cast<u16x8*>(&(xt)[(fp_ + 1)*40 + ng_*8]) = hi_; }

__global__ __launch_bounds__(512, 2) void k_attn(
    const float* __restrict__ x, const int* __restrict__ starts,
    const unsigned short* __restrict__ Aq,
    float* __restrict__ partO, float* __restrict__ partM, float* __restrict__ partL)
{
  __shared__ __align__(16) unsigned short xsub[2][32*264];  // [node][f] padded
  __shared__ __align__(16) unsigned short xT  [2][256*40];  // [f][node] padded
  __shared__ __align__(16) unsigned short Plds[128*40];     // [row][node] padded

  const int tid = threadIdx.x;
  const int wave = tid >> 6, lane = tid & 63, lg = lane >> 4, li = lane & 15;
  const int bid = blockIdx.x;
  const int g = bid >> 1, s = bid & 1;
  const int s0 = starts[g], s1 = starts[g+1];
  const int cntg = s1 - s0;
  const int half = (cntg + 1) >> 1;
  const int nstart = s0 + s*half;
  int cnt = cntg - s*half; cnt = cnt < 0 ? 0 : (cnt > half ? half : cnt);
  const int chunks = (cnt + 31) >> 5;
  const float* xg = x + (size_t)nstart*256;

  const int wavebase = (wave >> 1)*32 + (wave & 1)*16;  // first (h,q) row of this wave

  // Aq fragments (A operand: row=li, k=lg*8+j contiguous)
  bf16x8 afrag[8];
  {
    const unsigned short* ap = Aq + (size_t)(wavebase + li)*256 + lg*8;
    #pragma unroll
    for (int kb = 0; kb < 8; kb++)
      afrag[kb] = *reinterpret_cast<const bf16x8*>(ap + kb*32);
  }

  f32x4 oacc[16];
  #pragma unroll
  for (int i = 0; i < 16; i++) oacc[i] = f32x4{0.f,0.f,0.f,0.f};
  float rmax[4], rsum[4];
  #pragma unroll
  for (int r = 0; r < 4; r++){ rmax[r] = -1e30f; rsum[r] = 0.f; }

  float4 rA[4], rB[4];
  if (chunks > 0){
    LOADC(rA, 0);
    if (chunks > 1) LOADC(rB, 1);
    STAGE(xsub[0], rA);
    __syncthreads();
    BUILDT(xT[0], xsub[0]);
    if (chunks > 2) LOADC(rA, 2);
    __syncthreads();
  }

  for (int c = 0; c < chunks; ++c){
    const int cur = c & 1, nxt = cur ^ 1;
    // stage chunk c+1 into the other LDS buffer; re-issue loads for c+3
    if (c + 1 < chunks){
      if (c & 1){ STAGE(xsub[nxt], rA); if (c + 3 < chunks) LOADC(rA, c + 3); }
      else      { STAGE(xsub[nxt], rB); if (c + 3 < chunks) LOADC(rB, c + 3); }
    }

    const int c0 = c*32;
    // ---- S = Aq @ x^T ----
    f32x4 sacc0 = f32x4{0.f,0.f,0.f,0.f}, sacc1 = f32x4{0.f,0.f,0.f,0.f};
    #pragma unroll
    for (int kb = 0; kb < 8; kb++){
      const bf16x8 b0 = *reinterpret_cast<const bf16x8*>(&xsub[cur][li*264 + kb*32 + lg*8]);
      const bf16x8 b1 = *reinterpret_cast<const bf16x8*>(&xsub[cur][(16 + li)*264 + kb*32 + lg*8]);
      sacc0 = MFMA16(afrag[kb], b0, sacc0);
      sacc1 = MFMA16(afrag[kb], b1, sacc1);
    }
    if (c0 + li >= cnt)      { sacc0[0]=-1e30f; sacc0[1]=-1e30f; sacc0[2]=-1e30f; sacc0[3]=-1e30f; }
    if (c0 + 16 + li >= cnt) { sacc1[0]=-1e30f; sacc1[1]=-1e30f; sacc1[2]=-1e30f; sacc1[3]=-1e30f; }

    // ---- online softmax (exp2 domain), defer-max THR=8 ----
    #pragma unroll
    for (int r = 0; r < 4; r++){
      float cm = fmaxf(sacc0[r], sacc1[r]);
      cm = fmaxf(cm, __shfl_xor(cm, 1));
      cm = fmaxf(cm, __shfl_xor(cm, 2));
      cm = fmaxf(cm, __shfl_xor(cm, 4));
      cm = fmaxf(cm, __shfl_xor(cm, 8));
      if (cm > rmax[r] + 8.f){
        const float al = __builtin_exp2f(rmax[r] - cm);
        rmax[r] = cm;
        rsum[r] *= al;
        #pragma unroll
        for (int fi = 0; fi < 16; fi++) oacc[fi][r] *= al;
      }
      const float p0 = __builtin_exp2f(sacc0[r] - rmax[r]);
      const float p1 = __builtin_exp2f(sacc1[r] - rmax[r]);
      rsum[r] += p0 + p1;
      Plds[(wave*16 + lg*4 + r)*40 + li]      = f2bf(p0);
      Plds[(wave*16 + lg*4 + r)*40 + 16 + li] = f2bf(p1);
    }

    __syncthreads();   // xsub[nxt] + Plds visible
    if (c + 1 < chunks) BUILDT(xT[nxt], xsub[nxt]);

    // ---- PV: O += P(16x32) @ x(32x256) ----
    const bf16x8 pa = *reinterpret_cast<const bf16x8*>(&Plds[(wave*16 + li)*40 + lg*8]);
    #pragma unroll
    for (int fi = 0; fi < 16; fi++){
      const bf16x8 bv = *reinterpret_cast<const bf16x8*>(&xT[cur][(fi*16 + li)*40 + lg*8]);
      oacc[fi] = MFMA16(pa, bv, oacc[fi]);
    }
    __syncthreads();   // xT[nxt] ready; Plds/xsub free for next iter
  }

  // reduce row sums across the 16 column-lanes
  #pragma unroll
  for (int r = 0; r < 4; r++){
    float tt = rsum[r];
    tt += __shfl_xor(tt, 1); tt += __shfl_xor(tt, 2); tt += __shfl_xor(tt, 4); tt += __shfl_xor(tt, 8);
    rsum[r] = tt;
  }
  const int pbase = bid*128;
  #pragma unroll
  for (int r = 0; r < 4; r++){
    const int row = wavebase + lg*4 + r;
    #pragma unroll
    for (int fi = 0; fi < 16; fi++)
      partO[(size_t)(pbase + row)*256 + fi*16 + li] = oacc[fi][r];
    if (li == 0){ partM[pbase + row] = rmax[r]; partL[pbase + row] = rsum[r]; }
  }
}

// ---------------- combine partials + out-proj GEMM ----------------
__global__ __launch_bounds__(512, 1) void k_out(
    const float* __restrict__ partO, const float* __restrict__ partM, const float* __restrict__ partL,
    const unsigned short* __restrict__ Cmat, const float* __restrict__ cvec,
    float* __restrict__ out)
{
  __shared__ __align__(16) unsigned short plds[16*1024];  // [q'][(h,f)] XOR-swizzled
  __shared__ float s0s[64], s1s[64];
  const int tid = threadIdx.x;
  const int g = blockIdx.x >> 1, qh = blockIdx.x & 1;
  const int p0 = 2*g, p1 = 2*g + 1;
  if (tid < 64){
    const int h = tid >> 4, qr = tid & 15;
    const int row = h*32 + qh*16 + qr;
    const float m0 = partM[p0*128 + row], m1 = partM[p1*128 + row];
    const float M  = fmaxf(m0, m1);
    const float e0 = __builtin_exp2f(m0 - M), e1 = __builtin_exp2f(m1 - M);
    const float L  = e0*partL[p0*128 + row] + e1*partL[p1*128 + row];
    const float inv = 1.f / L;
    s0s[tid] = e0*inv; s1s[tid] = e1*inv;
  }
  __syncthreads();
  #pragma unroll
  for (int i = 0; i < 32; i++){
    const int idx = tid + i*512;
    const int col = idx & 1023, qr = idx >> 10;
    const int h = col >> 8, f = col & 255;
    const int row = h*32 + qh*16 + qr;
    const float v = s0s[h*16 + qr]*partO[(size_t)(p0*128 + row)*256 + f]
                  + s1s[h*16 + qr]*partO[(size_t)(p1*128 + row)*256 + f];
    const int bc = (col*2) ^ ((qr & 7) << 4);
    *reinterpret_cast<unsigned short*>(reinterpret_cast<char*>(plds) + qr*2048 + bc) = f2bf(v);
  }
  __syncthreads();
  const int wave = tid >> 6, lane = tid & 63, lg = lane >> 4, li = lane & 15;
  f32x4 acc0 = {0.f,0.f,0.f,0.f}, acc1 = {0.f,0.f,0.f,0.f};
  const float cv0 = cvec[wave*32 + li], cv1 = cvec[wave*32 + 16 + li];
  const unsigned short* cb0 = Cmat + (size_t)(wave*32 + li)*1024;
  const unsigned short* cb1 = Cmat + (size_t)(wave*32 + 16 + li)*1024;
  #pragma unroll 8
  for (int kb = 0; kb < 32; kb++){
    const int bc = ((kb*32 + lg*8)*2) ^ ((li & 7) << 4);
    const bf16x8 a  = *reinterpret_cast<const bf16x8*>(reinterpret_cast<const char*>(plds) + li*2048 + bc);
    const bf16x8 b0 = *reinterpret_cast<const bf16x8*>(cb0 + kb*32 + lg*8);
    const bf16x8 b1 = *reinterpret_cast<const bf16x8*>(cb1 + kb*32 + lg*8);
    acc0 = MFMA16(a, b0, acc0);
    acc1 = MFMA16(a, b1, acc1);
  }
  #pragma unroll
  for (int r = 0; r < 4; r++){
    const int q = lg*4 + r;
    const size_t orow = (size_t)(g*32 + qh*16 + q)*256;
    out[orow + wave*32 + li]      = acc0[r] + cv0;
    out[orow + wave*32 + 16 + li] = acc1[r] + cv1;
  }
}

// ---------------- launch ----------------

extern "C" void kernel_launch(void* const* d_in, const int* in_sizes, int n_in,
                              void* d_out, int out_size, void* d_ws, size_t ws_size,
                              hipStream_t stream)
{
  const float* x       = (const float*)d_in[0];
  const int*   batch   = (const int*)d_in[1];
  const float* queries = (const float*)d_in[2];
  const float* ipw     = (const float*)d_in[3];
  const float* ipb     = (const float*)d_in[4];
  const float* opw     = (const float*)d_in[5];
  const float* opb     = (const float*)d_in[6];
  float* out = (float*)d_out;
  const int total = in_sizes[1];

  char* w = (char*)d_ws;
  int*            starts = (int*)(w);
  unsigned short* Aq     = (unsigned short*)(w + 36*1024);
  unsigned short* Cmat   = (unsigned short*)(w + 102*1024);
  float*          cvec   = (float*)(w + 616*1024);
  float*          partO  = (float*)(w + (size_t)1024*1024);
  float*          partM  = (float*)(w + (size_t)1024*1024 + (size_t)256*128*256*4);
  float*          partL  = (float*)(w + (size_t)1024*1024 + (size_t)256*128*256*4 + 131072);

  k_prep<<<544, 256, 0, stream>>>(queries, ipw, ipb, opw, opb, batch, total,
                                  starts, Aq, Cmat, cvec);
  k_attn<<<256, 512, 0, stream>>>(x, starts, Aq, partO, partM, partL);
  k_out<<<256, 512, 0, stream>>>(partO, partM, partL, Cmat, cvec, out);
}

// Round 3
// 142.431 us; speedup vs baseline: 1.0989x; 1.0989x over previous
//
#include <hip/hip_runtime.h>
#include <hip/hip_bf16.h>

typedef __bf16 bf16x8 __attribute__((ext_vector_type(8)));
typedef float  f32x4  __attribute__((ext_vector_type(4)));
typedef unsigned short u16x8 __attribute__((ext_vector_type(8)));

#define MFMA16(a,b,c) __builtin_amdgcn_mfma_f32_16x16x32_bf16((a),(b),(c),0,0,0)

__device__ __forceinline__ unsigned short f2bf(float f){
  unsigned int u = __float_as_uint(f);
  u += 0x7fffu + ((u >> 16) & 1u);
  return (unsigned short)(u >> 16);
}

// raw barrier: LDS-visibility sync WITHOUT vmcnt(0) drain (keeps global loads in flight)
__device__ __forceinline__ void block_sync(){
  asm volatile("s_waitcnt lgkmcnt(0)" ::: "memory");
  __builtin_amdgcn_s_barrier();
}

constexpr float SCALE_LOG2E = 0.125f * 1.4426950408889634f; // 1/sqrt(64) * log2(e)

// ---------------- merged prep kernel ----------------
// blocks 0..31: qs + AqT fragments ; 32..287: Cmat+cvec ; 288..543: starts scan
__global__ void k_prep(const float* __restrict__ queries, const float* __restrict__ ipw,
                       const float* __restrict__ ipb, const float* __restrict__ opw,
                       const float* __restrict__ opb, const int* __restrict__ batch,
                       int total, int* __restrict__ starts,
                       unsigned short* __restrict__ AqF,
                       unsigned short* __restrict__ Cmat, float* __restrict__ cvec)
{
  __shared__ __align__(16) float sh[256];
  __shared__ __align__(16) float sh2[256];
  const int t = threadIdx.x, bid = blockIdx.x;

  if (bid < 32){
    // --- qs row q then AqT B-fragments for wave (h, q>>4) ---
    const int q = bid;
    sh[t] = queries[q*256 + t];
    __syncthreads();
    const float* wr = ipw + (size_t)t*256;
    float acc = 0.f;
    #pragma unroll 8
    for (int j = 0; j < 256; j += 4){
      float4 wv = *reinterpret_cast<const float4*>(wr + j);
      float4 qv = *reinterpret_cast<const float4*>(&sh[j]);
      acc += wv.x*qv.x + wv.y*qv.y + wv.z*qv.z + wv.w*qv.w;
    }
    sh2[t] = acc + ipb[t];
    __syncthreads();
    #pragma unroll
    for (int h = 0; h < 4; h++){
      const float* wk = ipw + (size_t)(256 + h*64)*256 + t;
      float a2 = 0.f;
      #pragma unroll 8
      for (int d = 0; d < 64; d++) a2 += sh2[h*64 + d] * wk[(size_t)d*256];
      // B-frag layout: AqF[w=h*2+qh][kb=f>>5][lane=((f>>3)&3)*16 + (q&15)][j=f&7]
      const int dst = ((h*2 + (q>>4))*8 + (t>>5))*512 + (((t>>3)&3)*16 + (q&15))*8 + (t&7);
      AqF[dst] = f2bf(a2 * SCALE_LOG2E);
    }
  } else if (bid < 288){
    // --- Cmat row g + cvec[g] ---
    const int g = bid - 32;
    sh[t] = opw[(size_t)g*256 + t];
    __syncthreads();
    #pragma unroll
    for (int h = 0; h < 4; h++){
      const float* wv = ipw + (size_t)(512 + h*64)*256 + t;
      float acc = 0.f;
      #pragma unroll 8
      for (int d = 0; d < 64; d++) acc += wv[(size_t)d*256] * sh[h*64 + d];
      Cmat[(size_t)g*1024 + h*256 + t] = f2bf(acc);
    }
    sh2[t] = ipb[512 + t] * sh[t];
    __syncthreads();
    for (int off = 128; off > 0; off >>= 1){
      if (t < off) sh2[t] += sh2[t + off];
      __syncthreads();
    }
    if (t == 0) cvec[g] = sh2[0] + opb[g];
  } else {
    // --- parallel boundary scan ---
    const int sb = bid - 288;
    const int i0 = sb*1024 + t*4;
    if (i0 + 3 < total){
      if (i0 == 0) starts[0] = 0;
      const int4 b4 = *reinterpret_cast<const int4*>(batch + i0);
      if (b4.y != b4.x) starts[b4.y] = i0 + 1;
      if (b4.z != b4.y) starts[b4.z] = i0 + 2;
      if (b4.w != b4.z) starts[b4.w] = i0 + 3;
      if (i0 + 4 < total){
        const int nxt = batch[i0 + 4];
        if (nxt != b4.w) starts[nxt] = i0 + 4;
      } else {
        starts[128] = total;
      }
    }
  }
}

// ---------------- fused flash attention over raw x ----------------
// grid 256 = graph*2 splits, 512 threads (8 waves).
// S phase : wave w owns row-tile w (16 (h,q) rows), swapped mfma(x, AqT) -> lane-local softmax.
// PV phase: wave w owns f-slice [w*32, w*32+32) for ALL 128 rows.

#define LOADC(dst, c_) { \
  const int c0_ = (c_)*32; \
  _Pragma("unroll") \
  for (int k = 0; k < 4; k++){ \
    const int node_ = (tid >> 6) + 8*k; \
    const int nl_ = c0_ + node_; \
    float4 v_ = make_float4(0.f,0.f,0.f,0.f); \
    if (nl_ < cnt) v_ = *reinterpret_cast<const float4*>(xg + (size_t)nl_*256 + (tid & 63)*4); \
    dst[k] = v_; } }

#define STAGE(buf, src) { \
  _Pragma("unroll") \
  for (int k = 0; k < 4; k++){ \
    const int node_ = (tid >> 6) + 8*k; \
    const unsigned short b0_ = f2bf(src[k].x), b1_ = f2bf(src[k].y); \
    const unsigned short b2_ = f2bf(src[k].z), b3_ = f2bf(src[k].w); \
    *reinterpret_cast<ushort4*>(&(buf)[node_*264 + (tid & 63)*4]) = make_ushort4(b0_,b1_,b2_,b3_); } }

// transpose xsub[node][f] -> xT[f][node] (pad 40)
#define BUILDT(xt, xs) { \
  const int fp_ = (tid & 127)*2, ng_ = tid >> 7; \
  unsigned int w_[8]; \
  _Pragma("unroll") \
  for (int r = 0; r < 8; r++) w_[r] = *reinterpret_cast<const unsigned int*>(&(xs)[(ng_*8 + r)*264 + fp_]); \
  u16x8 lo_, hi_; \
  _Pragma("unroll") \
  for (int r = 0; r < 8; r++){ lo_[r] = (unsigned short)(w_[r] & 0xffffu); hi_[r] = (unsigned short)(w_[r] >> 16); } \
  *reinterpret_cast<u16x8*>(&(xt)[fp_*40 + ng_*8])       = lo_; \
  *reinterpret_cast<u16x8*>(&(xt)[(fp_ + 1)*40 + ng_*8]) = hi_; }

__global__ __launch_bounds__(512, 2) void k_attn(
    const float* __restrict__ x, const int* __restrict__ starts,
    const unsigned short* __restrict__ AqF,
    float* __restrict__ partO, float* __restrict__ partM, float* __restrict__ partL)
{
  __shared__ __align__(16) unsigned short xsub[2][32*264];  // [node][f] padded
  __shared__ __align__(16) unsigned short xT  [2][256*40];  // [f][node] padded
  __shared__ __align__(16) unsigned short Plds[128*40];     // [row][node] padded
  __shared__ __align__(16) float alds[128];                 // per-row rescale

  const int tid = threadIdx.x;
  const int wave = tid >> 6, lane = tid & 63, lg = lane >> 4, li = lane & 15;
  const int nb = lg*4;
  const int bid = blockIdx.x;
  const int g = bid >> 1, s = bid & 1;
  const int s0 = starts[g], s1 = starts[g+1];
  const int cntg = s1 - s0;
  const int half = (cntg + 1) >> 1;
  const int nstart = s0 + s*half;
  int cnt = cntg - s*half; cnt = cnt < 0 ? 0 : (cnt > half ? half : cnt);
  const int chunks = (cnt + 31) >> 5;
  const float* xg = x + (size_t)nstart*256;

  const int wavebase = (wave >> 1)*32 + (wave & 1)*16;  // first global row of this wave's row-tile

  // AqT B-fragments for this wave's 16 q-rows (precomputed in k_prep)
  bf16x8 bfragS[8];
  {
    const unsigned short* ap = AqF + (size_t)(wave*8)*512 + lane*8;
    #pragma unroll
    for (int kb = 0; kb < 8; kb++)
      bfragS[kb] = *reinterpret_cast<const bf16x8*>(ap + kb*512);
  }

  f32x4 oacc[16];  // [rowtile 8][ftile 2]
  #pragma unroll
  for (int i = 0; i < 16; i++) oacc[i] = f32x4{0.f,0.f,0.f,0.f};
  float rmax = -1e30f, rsum = 0.f;

  float4 rA[4], rB[4];
  if (chunks > 0){
    LOADC(rA, 0);
    if (chunks > 1) LOADC(rB, 1);
    STAGE(xsub[0], rA);
    if (chunks > 2) LOADC(rA, 2);
    block_sync();
    BUILDT(xT[0], xsub[0]);
  }

  for (int c = 0; c < chunks; ++c){
    const int cur = c & 1, nxt = cur ^ 1;
    if (c + 1 < chunks){
      if (c & 1){ STAGE(xsub[nxt], rA); if (c + 3 < chunks) LOADC(rA, c + 3); }
      else      { STAGE(xsub[nxt], rB); if (c + 3 < chunks) LOADC(rB, c + 3); }
    }

    // ---- S^T = x @ AqT : C[node][q], lane owns q = li, nodes nb+r (+16) ----
    f32x4 sc0 = f32x4{0.f,0.f,0.f,0.f}, sc1 = f32x4{0.f,0.f,0.f,0.f};
    #pragma unroll
    for (int kb = 0; kb < 8; kb++){
      const bf16x8 a0 = *reinterpret_cast<const bf16x8*>(&xsub[cur][li*264 + kb*32 + lg*8]);
      const bf16x8 a1 = *reinterpret_cast<const bf16x8*>(&xsub[cur][(16 + li)*264 + kb*32 + lg*8]);
      sc0 = MFMA16(a0, bfragS[kb], sc0);
      sc1 = MFMA16(a1, bfragS[kb], sc1);
    }
    const int c0 = c*32;
    #pragma unroll
    for (int r = 0; r < 4; r++){
      if (c0 + nb + r >= cnt)      sc0[r] = -1e30f;
      if (c0 + 16 + nb + r >= cnt) sc1[r] = -1e30f;
    }

    // ---- lane-local online softmax (q = li) ----
    float cm = fmaxf(fmaxf(fmaxf(sc0[0],sc0[1]),fmaxf(sc0[2],sc0[3])),
                     fmaxf(fmaxf(sc1[0],sc1[1]),fmaxf(sc1[2],sc1[3])));
    cm = fmaxf(cm, __shfl_xor(cm, 16));
    cm = fmaxf(cm, __shfl_xor(cm, 32));
    const float nm = fmaxf(rmax, cm);
    const float al = __builtin_exp2f(rmax - nm);
    rmax = nm;
    float ps = 0.f;
    unsigned short pb[8];
    #pragma unroll
    for (int r = 0; r < 4; r++){
      const float p0 = __builtin_exp2f(sc0[r] - nm);
      const float p1 = __builtin_exp2f(sc1[r] - nm);
      ps += p0 + p1;
      pb[r] = f2bf(p0); pb[4+r] = f2bf(p1);
    }
    rsum = rsum*al + ps;
    *reinterpret_cast<ushort4*>(&Plds[(wavebase + li)*40 + nb])      = make_ushort4(pb[0],pb[1],pb[2],pb[3]);
    *reinterpret_cast<ushort4*>(&Plds[(wavebase + li)*40 + 16 + nb]) = make_ushort4(pb[4],pb[5],pb[6],pb[7]);
    if (lg == 0) alds[wavebase + li] = al;

    block_sync();   // BAR1: xsub[nxt], Plds, alds visible
    if (c + 1 < chunks) BUILDT(xT[nxt], xsub[nxt]);

    // ---- PV: wave owns f-slice [wave*32, wave*32+32) for all 128 rows ----
    const bf16x8 bv0 = *reinterpret_cast<const bf16x8*>(&xT[cur][(wave*32 + li)*40 + lg*8]);
    const bf16x8 bv1 = *reinterpret_cast<const bf16x8*>(&xT[cur][(wave*32 + 16 + li)*40 + lg*8]);
    #pragma unroll
    for (int rt = 0; rt < 8; rt++){
      const f32x4 alv = *reinterpret_cast<const f32x4*>(&alds[rt*16 + nb]);
      const bf16x8 pa = *reinterpret_cast<const bf16x8*>(&Plds[(rt*16 + li)*40 + lg*8]);
      #pragma unroll
      for (int r = 0; r < 4; r++){ oacc[rt*2][r] *= alv[r]; oacc[rt*2+1][r] *= alv[r]; }
      oacc[rt*2]   = MFMA16(pa, bv0, oacc[rt*2]);
      oacc[rt*2+1] = MFMA16(pa, bv1, oacc[rt*2+1]);
    }
    block_sync();   // BAR2: PV done; buffers free for next iter
  }

  // final row-sum reduce across the 4 lane-groups
  rsum += __shfl_xor(rsum, 16);
  rsum += __shfl_xor(rsum, 32);

  const int pbase = bid*128;
  if (lane < 16){
    partM[pbase + wavebase + li] = rmax;
    partL[pbase + wavebase + li] = rsum;
  }
  #pragma unroll
  for (int rt = 0; rt < 8; rt++){
    #pragma unroll
    for (int r = 0; r < 4; r++){
      const size_t orow = (size_t)(pbase + rt*16 + nb + r)*256;
      partO[orow + wave*32 + li]      = oacc[rt*2][r];
      partO[orow + wave*32 + 16 + li] = oacc[rt*2+1][r];
    }
  }
}

// ---------------- combine partials + out-proj GEMM ----------------
__global__ __launch_bounds__(512, 1) void k_out(
    const float* __restrict__ partO, const float* __restrict__ partM, const float* __restrict__ partL,
    const unsigned short* __restrict__ Cmat, const float* __restrict__ cvec,
    float* __restrict__ out)
{
  __shared__ __align__(16) unsigned short plds[16*1024];  // [q'][(h,f)] XOR-swizzled
  __shared__ float s0s[64], s1s[64];
  const int tid = threadIdx.x;
  const int g = blockIdx.x >> 1, qh = blockIdx.x & 1;
  const int p0 = 2*g, p1 = 2*g + 1;
  if (tid < 64){
    const int h = tid >> 4, qr = tid & 15;
    const int row = h*32 + qh*16 + qr;
    const float m0 = partM[p0*128 + row], m1 = partM[p1*128 + row];
    const float M  = fmaxf(m0, m1);
    const float e0 = __builtin_exp2f(m0 - M), e1 = __builtin_exp2f(m1 - M);
    const float L  = e0*partL[p0*128 + row] + e1*partL[p1*128 + row];
    const float inv = 1.f / L;
    s0s[tid] = e0*inv; s1s[tid] = e1*inv;
  }
  __syncthreads();
  #pragma unroll
  for (int i = 0; i < 32; i++){
    const int idx = tid + i*512;
    const int col = idx & 1023, qr = idx >> 10;
    const int h = col >> 8, f = col & 255;
    const int row = h*32 + qh*16 + qr;
    const float v = s0s[h*16 + qr]*partO[(size_t)(p0*128 + row)*256 + f]
                  + s1s[h*16 + qr]*partO[(size_t)(p1*128 + row)*256 + f];
    const int bc = (col*2) ^ ((qr & 7) << 4);
    *reinterpret_cast<unsigned short*>(reinterpret_cast<char*>(plds) + qr*2048 + bc) = f2bf(v);
  }
  __syncthreads();
  const int wave = tid >> 6, lane = tid & 63, lg = lane >> 4, li = lane & 15;
  f32x4 acc0 = {0.f,0.f,0.f,0.f}, acc1 = {0.f,0.f,0.f,0.f};
  const float cv0 = cvec[wave*32 + li], cv1 = cvec[wave*32 + 16 + li];
  const unsigned short* cb0 = Cmat + (size_t)(wave*32 + li)*1024;
  const unsigned short* cb1 = Cmat + (size_t)(wave*32 + 16 + li)*1024;
  #pragma unroll 8
  for (int kb = 0; kb < 32; kb++){
    const int bc = ((kb*32 + lg*8)*2) ^ ((li & 7) << 4);
    const bf16x8 a  = *reinterpret_cast<const bf16x8*>(reinterpret_cast<const char*>(plds) + li*2048 + bc);
    const bf16x8 b0 = *reinterpret_cast<const bf16x8*>(cb0 + kb*32 + lg*8);
    const bf16x8 b1 = *reinterpret_cast<const bf16x8*>(cb1 + kb*32 + lg*8);
    acc0 = MFMA16(a, b0, acc0);
    acc1 = MFMA16(a, b1, acc1);
  }
  #pragma unroll
  for (int r = 0; r < 4; r++){
    const int q = lg*4 + r;
    const size_t orow = (size_t)(g*32 + qh*16 + q)*256;
    out[orow + wave*32 + li]      = acc0[r] + cv0;
    out[orow + wave*32 + 16 + li] = acc1[r] + cv1;
  }
}

// ---------------- launch ----------------

extern "C" void kernel_launch(void* const* d_in, const int* in_sizes, int n_in,
                              void* d_out, int out_size, void* d_ws, size_t ws_size,
                              hipStream_t stream)
{
  const float* x       = (const float*)d_in[0];
  const int*   batch   = (const int*)d_in[1];
  const float* queries = (const float*)d_in[2];
  const float* ipw     = (const float*)d_in[3];
  const float* ipb     = (const float*)d_in[4];
  const float* opw     = (const float*)d_in[5];
  const float* opb     = (const float*)d_in[6];
  float* out = (float*)d_out;
  const int total = in_sizes[1];

  char* w = (char*)d_ws;
  int*            starts = (int*)(w);
  unsigned short* AqF    = (unsigned short*)(w + 36*1024);   // 64 KB
  unsigned short* Cmat   = (unsigned short*)(w + 102*1024);  // 512 KB
  float*          cvec   = (float*)(w + 616*1024);
  float*          partO  = (float*)(w + (size_t)1024*1024);
  float*          partM  = (float*)(w + (size_t)1024*1024 + (size_t)256*128*256*4);
  float*          partL  = (float*)(w + (size_t)1024*1024 + (size_t)256*128*256*4 + 131072);

  k_prep<<<544, 256, 0, stream>>>(queries, ipw, ipb, opw, opb, batch, total,
                                  starts, AqF, Cmat, cvec);
  k_attn<<<256, 512, 0, stream>>>(x, starts, AqF, partO, partM, partL);
  k_out<<<256, 512, 0, stream>>>(partO, partM, partL, Cmat, cvec, out);
}

// Round 4
// 133.384 us; speedup vs baseline: 1.1734x; 1.0678x over previous
//
#include <hip/hip_runtime.h>
#include <hip/hip_bf16.h>

typedef __bf16 bf16x8 __attribute__((ext_vector_type(8)));
typedef float  f32x4  __attribute__((ext_vector_type(4)));

#define MFMA16(a,b,c) __builtin_amdgcn_mfma_f32_16x16x32_bf16((a),(b),(c),0,0,0)

__device__ __forceinline__ unsigned short f2bf(float f){
  unsigned int u = __float_as_uint(f);
  u += 0x7fffu + ((u >> 16) & 1u);
  return (unsigned short)(u >> 16);
}

// LDS-visibility sync WITHOUT vmcnt(0) drain (keeps global loads in flight)
__device__ __forceinline__ void block_sync(){
  asm volatile("s_waitcnt lgkmcnt(0)" ::: "memory");
  __builtin_amdgcn_s_barrier();
}

constexpr float SCALE_LOG2E = 0.125f * 1.4426950408889634f; // 1/sqrt(64) * log2(e)

// ---------------- merged prep kernel ----------------
// blocks 0..31: qs + AqT fragments ; 32..287: Cmat+cvec ; 288..543: starts scan
__global__ void k_prep(const float* __restrict__ queries, const float* __restrict__ ipw,
                       const float* __restrict__ ipb, const float* __restrict__ opw,
                       const float* __restrict__ opb, const int* __restrict__ batch,
                       int total, int* __restrict__ starts,
                       unsigned short* __restrict__ AqF,
                       unsigned short* __restrict__ Cmat, float* __restrict__ cvec)
{
  __shared__ __align__(16) float sh[256];
  __shared__ __align__(16) float sh2[256];
  const int t = threadIdx.x, bid = blockIdx.x;

  if (bid < 32){
    const int q = bid;
    sh[t] = queries[q*256 + t];
    __syncthreads();
    const float* wr = ipw + (size_t)t*256;
    float acc = 0.f;
    #pragma unroll 8
    for (int j = 0; j < 256; j += 4){
      float4 wv = *reinterpret_cast<const float4*>(wr + j);
      float4 qv = *reinterpret_cast<const float4*>(&sh[j]);
      acc += wv.x*qv.x + wv.y*qv.y + wv.z*qv.z + wv.w*qv.w;
    }
    sh2[t] = acc + ipb[t];
    __syncthreads();
    #pragma unroll
    for (int h = 0; h < 4; h++){
      const float* wk = ipw + (size_t)(256 + h*64)*256 + t;
      float a2 = 0.f;
      #pragma unroll 8
      for (int d = 0; d < 64; d++) a2 += sh2[h*64 + d] * wk[(size_t)d*256];
      // B-frag layout: AqF[w=h*2+qh][kb=f>>5][lane=((f>>3)&3)*16 + (q&15)][j=f&7]
      const int dst = ((h*2 + (q>>4))*8 + (t>>5))*512 + (((t>>3)&3)*16 + (q&15))*8 + (t&7);
      AqF[dst] = f2bf(a2 * SCALE_LOG2E);
    }
  } else if (bid < 288){
    const int g = bid - 32;
    sh[t] = opw[(size_t)g*256 + t];
    __syncthreads();
    #pragma unroll
    for (int h = 0; h < 4; h++){
      const float* wv = ipw + (size_t)(512 + h*64)*256 + t;
      float acc = 0.f;
      #pragma unroll 8
      for (int d = 0; d < 64; d++) acc += wv[(size_t)d*256] * sh[h*64 + d];
      Cmat[(size_t)g*1024 + h*256 + t] = f2bf(acc);
    }
    sh2[t] = ipb[512 + t] * sh[t];
    __syncthreads();
    for (int off = 128; off > 0; off >>= 1){
      if (t < off) sh2[t] += sh2[t + off];
      __syncthreads();
    }
    if (t == 0) cvec[g] = sh2[0] + opb[g];
  } else {
    const int sb = bid - 288;
    const int i0 = sb*1024 + t*4;
    if (i0 + 3 < total){
      if (i0 == 0) starts[0] = 0;
      const int4 b4 = *reinterpret_cast<const int4*>(batch + i0);
      if (b4.y != b4.x) starts[b4.y] = i0 + 1;
      if (b4.z != b4.y) starts[b4.z] = i0 + 2;
      if (b4.w != b4.z) starts[b4.w] = i0 + 3;
      if (i0 + 4 < total){
        const int nxt = batch[i0 + 4];
        if (nxt != b4.w) starts[nxt] = i0 + 4;
      } else {
        starts[128] = total;
      }
    }
  }
}

// ---------------- fused flash attention over raw x ----------------
// grid 256 = graph*2 splits, 512 threads (8 waves).
// S phase : wave w owns row-tile w (16 (h,q) rows), swapped mfma(x, AqT) -> lane-local softmax.
// PV phase: wave w owns f-slice [w*32, w*32+32) for ALL 128 rows.
// One barrier per chunk; xsub[2], xT[3], Plds[2], alds[2] buffering.

// thread handles nodes nb4..nb4+3 (nb4 = wave*4), f-quad fq (= lane)
#define LOADC(dst, c_) { \
  const int c0_ = (c_)*32; \
  _Pragma("unroll") \
  for (int n = 0; n < 4; n++){ \
    const int nl_ = c0_ + nb4 + n; \
    float4 v_ = make_float4(0.f,0.f,0.f,0.f); \
    if (nl_ < cnt) v_ = *reinterpret_cast<const float4*>(xg + (size_t)nl_*256 + fq*4); \
    dst[n] = v_; } }

// register 4x4 transpose -> write xsub [node][f] (pad 264) AND xT [f][node] (pad 40, XOR swizzle)
#define STAGE(xsP, xtP, src) { \
  unsigned short b_[4][4]; \
  _Pragma("unroll") \
  for (int n = 0; n < 4; n++){ \
    b_[n][0] = f2bf(src[n].x); b_[n][1] = f2bf(src[n].y); \
    b_[n][2] = f2bf(src[n].z); b_[n][3] = f2bf(src[n].w); } \
  _Pragma("unroll") \
  for (int n = 0; n < 4; n++) \
    *reinterpret_cast<ushort4*>(&(xsP)[(nb4 + n)*264 + fq*4]) = \
        make_ushort4(b_[n][0], b_[n][1], b_[n][2], b_[n][3]); \
  _Pragma("unroll") \
  for (int j = 0; j < 4; j++){ \
    const int row_ = fq*4 + j; \
    int byte_ = row_*80 + nb4*2; byte_ ^= ((row_>>2)&7)<<4; \
    *reinterpret_cast<ushort4*>(reinterpret_cast<char*>(xtP) + byte_) = \
        make_ushort4(b_[0][j], b_[1][j], b_[2][j], b_[3][j]); } }

__global__ __launch_bounds__(512, 2) void k_attn(
    const float* __restrict__ x, const int* __restrict__ starts,
    const unsigned short* __restrict__ AqF,
    float* __restrict__ partO, float* __restrict__ partM, float* __restrict__ partL)
{
  __shared__ __align__(16) unsigned short xsub[2][32*264];
  __shared__ __align__(16) unsigned short xT  [3][256*40];
  __shared__ __align__(16) unsigned short Plds[2][128*40];
  __shared__ __align__(16) float alds[2][128];
  __shared__ __align__(8)  unsigned char flags[2][8];

  const int tid = threadIdx.x;
  const int wave = tid >> 6, lane = tid & 63, lg = lane >> 4, li = lane & 15;
  const int nb = lg*4;
  const int nb4 = wave*4, fq = lane;
  const int bid = blockIdx.x;
  const int g = bid >> 1, s = bid & 1;
  const int s0 = starts[g], s1 = starts[g+1];
  const int cntg = s1 - s0;
  const int half = (cntg + 1) >> 1;
  const int nstart = s0 + s*half;
  int cnt = cntg - s*half; cnt = cnt < 0 ? 0 : (cnt > half ? half : cnt);
  const int chunks = (cnt + 31) >> 5;
  const float* xg = x + (size_t)nstart*256;

  const int wavebase = (wave >> 1)*32 + (wave & 1)*16;

  // AqT B-fragments (precomputed layout in k_prep)
  bf16x8 bfragS[8];
  {
    const unsigned short* ap = AqF + (size_t)(wave*8)*512 + lane*8;
    #pragma unroll
    for (int kb = 0; kb < 8; kb++)
      bfragS[kb] = *reinterpret_cast<const bf16x8*>(ap + kb*512);
  }

  f32x4 oacc[16];  // [rowtile 8][ftile 2]
  #pragma unroll
  for (int i = 0; i < 16; i++) oacc[i] = f32x4{0.f,0.f,0.f,0.f};
  float rmax = -1e30f, rsum = 0.f;

  // PV bv addresses (fixed per thread)
  int bvb0 = (wave*32 + li)*80 + lg*16;      bvb0 ^= (((wave*32 + li)>>2)&7)<<4;
  int bvb1 = (wave*32 + 16 + li)*80 + lg*16; bvb1 ^= (((wave*32 + 16 + li)>>2)&7)<<4;

  float4 rA[4], rB[4];
  if (chunks > 0){
    LOADC(rA, 0);
    if (chunks > 1) LOADC(rB, 1);
    STAGE(xsub[0], xT[0], rA);
    if (chunks > 2) LOADC(rA, 2);
    block_sync();
  }

  int cur3 = 0;
  for (int c = 0; c < chunks; ++c){
    const int cur2 = c & 1;
    const int nxt3 = (cur3 == 2) ? 0 : cur3 + 1;
    // ---- pre-barrier: stage chunk c+1, refill regs with c+3 ----
    if (c + 1 < chunks){
      unsigned short* xsP = xsub[cur2 ^ 1];
      unsigned short* xtP = xT[nxt3];
      if (c & 1){ STAGE(xsP, xtP, rA); if (c + 3 < chunks) LOADC(rA, c + 3); }
      else      { STAGE(xsP, xtP, rB); if (c + 3 < chunks) LOADC(rB, c + 3); }
    }

    // ---- S^T = x @ AqT : lane owns q = li, nodes nb+r (+16) ----
    f32x4 sc0 = f32x4{0.f,0.f,0.f,0.f}, sc1 = f32x4{0.f,0.f,0.f,0.f};
    #pragma unroll
    for (int kb = 0; kb < 8; kb++){
      const bf16x8 a0 = *reinterpret_cast<const bf16x8*>(&xsub[cur2][li*264 + kb*32 + lg*8]);
      const bf16x8 a1 = *reinterpret_cast<const bf16x8*>(&xsub[cur2][(16 + li)*264 + kb*32 + lg*8]);
      sc0 = MFMA16(a0, bfragS[kb], sc0);
      sc1 = MFMA16(a1, bfragS[kb], sc1);
    }
    const int c0 = c*32;
    #pragma unroll
    for (int r = 0; r < 4; r++){
      if (c0 + nb + r >= cnt)      sc0[r] = -1e30f;
      if (c0 + 16 + nb + r >= cnt) sc1[r] = -1e30f;
    }

    // ---- lane-local online softmax, defer-max THR=8 ----
    float cm = fmaxf(fmaxf(fmaxf(sc0[0],sc0[1]),fmaxf(sc0[2],sc0[3])),
                     fmaxf(fmaxf(sc1[0],sc1[1]),fmaxf(sc1[2],sc1[3])));
    cm = fmaxf(cm, __shfl_xor(cm, 16));
    cm = fmaxf(cm, __shfl_xor(cm, 32));
    float al = 1.f;
    int resc = 0;
    if (cm > rmax + 8.f){
      al = __builtin_exp2f(rmax - cm);
      rmax = cm;
      rsum *= al;
      resc = 1;
    }
    float ps = 0.f;
    unsigned short pb[8];
    #pragma unroll
    for (int r = 0; r < 4; r++){
      const float p0 = __builtin_exp2f(sc0[r] - rmax);
      const float p1 = __builtin_exp2f(sc1[r] - rmax);
      ps += p0 + p1;
      pb[r] = f2bf(p0); pb[4+r] = f2bf(p1);
    }
    rsum += ps;
    *reinterpret_cast<ushort4*>(&Plds[cur2][(wavebase + li)*40 + nb])      = make_ushort4(pb[0],pb[1],pb[2],pb[3]);
    *reinterpret_cast<ushort4*>(&Plds[cur2][(wavebase + li)*40 + 16 + nb]) = make_ushort4(pb[4],pb[5],pb[6],pb[7]);
    if (lg == 0) alds[cur2][wavebase + li] = al;
    const int anyresc = __any(resc);
    if (lane == 0) flags[cur2][wave] = (unsigned char)anyresc;

    block_sync();   // single barrier per chunk

    // ---- PV: wave owns f-slice [wave*32, wave*32+32) for all 128 rows ----
    const uint2 fl = *reinterpret_cast<const uint2*>(&flags[cur2][0]);
    if ((fl.x | fl.y) != 0){
      #pragma unroll
      for (int rt = 0; rt < 8; rt++){
        const f32x4 alv = *reinterpret_cast<const f32x4*>(&alds[cur2][rt*16 + nb]);
        #pragma unroll
        for (int r = 0; r < 4; r++){ oacc[rt*2][r] *= alv[r]; oacc[rt*2+1][r] *= alv[r]; }
      }
    }
    const char* xtC = reinterpret_cast<const char*>(xT[cur3]);
    const bf16x8 bv0 = *reinterpret_cast<const bf16x8*>(xtC + bvb0);
    const bf16x8 bv1 = *reinterpret_cast<const bf16x8*>(xtC + bvb1);
    #pragma unroll
    for (int rt = 0; rt < 8; rt++){
      const bf16x8 pa = *reinterpret_cast<const bf16x8*>(&Plds[cur2][(rt*16 + li)*40 + lg*8]);
      oacc[rt*2]   = MFMA16(pa, bv0, oacc[rt*2]);
      oacc[rt*2+1] = MFMA16(pa, bv1, oacc[rt*2+1]);
    }
    cur3 = nxt3;
  }

  // final row-sum reduce across the 4 lane-groups
  rsum += __shfl_xor(rsum, 16);
  rsum += __shfl_xor(rsum, 32);

  const int pbase = bid*128;
  if (lane < 16){
    partM[pbase + wavebase + li] = rmax;
    partL[pbase + wavebase + li] = rsum;
  }
  #pragma unroll
  for (int rt = 0; rt < 8; rt++){
    #pragma unroll
    for (int r = 0; r < 4; r++){
      const size_t orow = (size_t)(pbase + rt*16 + nb + r)*256;
      partO[orow + wave*32 + li]      = oacc[rt*2][r];
      partO[orow + wave*32 + 16 + li] = oacc[rt*2+1][r];
    }
  }
}

// ---------------- combine partials + out-proj GEMM ----------------
__global__ __launch_bounds__(512, 1) void k_out(
    const float* __restrict__ partO, const float* __restrict__ partM, const float* __restrict__ partL,
    const unsigned short* __restrict__ Cmat, const float* __restrict__ cvec,
    float* __restrict__ out)
{
  __shared__ __align__(16) unsigned short plds[16*1024];
  __shared__ float s0s[64], s1s[64];
  const int tid = threadIdx.x;
  const int g = blockIdx.x >> 1, qh = blockIdx.x & 1;
  const int p0 = 2*g, p1 = 2*g + 1;
  if (tid < 64){
    const int h = tid >> 4, qr = tid & 15;
    const int row = h*32 + qh*16 + qr;
    const float m0 = partM[p0*128 + row], m1 = partM[p1*128 + row];
    const float M  = fmaxf(m0, m1);
    const float e0 = __builtin_exp2f(m0 - M), e1 = __builtin_exp2f(m1 - M);
    const float L  = e0*partL[p0*128 + row] + e1*partL[p1*128 + row];
    const float inv = 1.f / L;
    s0s[tid] = e0*inv; s1s[tid] = e1*inv;
  }
  __syncthreads();
  #pragma unroll
  for (int i = 0; i < 32; i++){
    const int idx = tid + i*512;
    const int col = idx & 1023, qr = idx >> 10;
    const int h = col >> 8, f = col & 255;
    const int row = h*32 + qh*16 + qr;
    const float v = s0s[h*16 + qr]*partO[(size_t)(p0*128 + row)*256 + f]
                  + s1s[h*16 + qr]*partO[(size_t)(p1*128 + row)*256 + f];
    const int bc = (col*2) ^ ((qr & 7) << 4);
    *reinterpret_cast<unsigned short*>(reinterpret_cast<char*>(plds) + qr*2048 + bc) = f2bf(v);
  }
  __syncthreads();
  const int wave = tid >> 6, lane = tid & 63, lg = lane >> 4, li = lane & 15;
  f32x4 acc0 = {0.f,0.f,0.f,0.f}, acc1 = {0.f,0.f,0.f,0.f};
  const float cv0 = cvec[wave*32 + li], cv1 = cvec[wave*32 + 16 + li];
  const unsigned short* cb0 = Cmat + (size_t)(wave*32 + li)*1024;
  const unsigned short* cb1 = Cmat + (size_t)(wave*32 + 16 + li)*1024;
  #pragma unroll 8
  for (int kb = 0; kb < 32; kb++){
    const int bc = ((kb*32 + lg*8)*2) ^ ((li & 7) << 4);
    const bf16x8 a  = *reinterpret_cast<const bf16x8*>(reinterpret_cast<const char*>(plds) + li*2048 + bc);
    const bf16x8 b0 = *reinterpret_cast<const bf16x8*>(cb0 + kb*32 + lg*8);
    const bf16x8 b1 = *reinterpret_cast<const bf16x8*>(cb1 + kb*32 + lg*8);
    acc0 = MFMA16(a, b0, acc0);
    acc1 = MFMA16(a, b1, acc1);
  }
  #pragma unroll
  for (int r = 0; r < 4; r++){
    const int q = lg*4 + r;
    const size_t orow = (size_t)(g*32 + qh*16 + q)*256;
    out[orow + wave*32 + li]      = acc0[r] + cv0;
    out[orow + wave*32 + 16 + li] = acc1[r] + cv1;
  }
}

// ---------------- launch ----------------

extern "C" void kernel_launch(void* const* d_in, const int* in_sizes, int n_in,
                              void* d_out, int out_size, void* d_ws, size_t ws_size,
                              hipStream_t stream)
{
  const float* x       = (const float*)d_in[0];
  const int*   batch   = (const int*)d_in[1];
  const float* queries = (const float*)d_in[2];
  const float* ipw     = (const float*)d_in[3];
  const float* ipb     = (const float*)d_in[4];
  const float* opw     = (const float*)d_in[5];
  const float* opb     = (const float*)d_in[6];
  float* out = (float*)d_out;
  const int total = in_sizes[1];

  char* w = (char*)d_ws;
  int*            starts = (int*)(w);
  unsigned short* AqF    = (unsigned short*)(w + 36*1024);
  unsigned short* Cmat   = (unsigned short*)(w + 102*1024);
  float*          cvec   = (float*)(w + 616*1024);
  float*          partO  = (float*)(w + (size_t)1024*1024);
  float*          partM  = (float*)(w + (size_t)1024*1024 + (size_t)256*128*256*4);
  float*          partL  = (float*)(w + (size_t)1024*1024 + (size_t)256*128*256*4 + 131072);

  k_prep<<<544, 256, 0, stream>>>(queries, ipw, ipb, opw, opb, batch, total,
                                  starts, AqF, Cmat, cvec);
  k_attn<<<256, 512, 0, stream>>>(x, starts, AqF, partO, partM, partL);
  k_out<<<256, 512, 0, stream>>>(partO, partM, partL, Cmat, cvec, out);
}

// Round 5
// 113.761 us; speedup vs baseline: 1.3758x; 1.1725x over previous
//
#include <hip/hip_runtime.h>
#include <hip/hip_bf16.h>

typedef __bf16 bf16x8 __attribute__((ext_vector_type(8)));
typedef float  f32x4  __attribute__((ext_vector_type(4)));

#define MFMA16(a,b,c) __builtin_amdgcn_mfma_f32_16x16x32_bf16((a),(b),(c),0,0,0)

__device__ __forceinline__ unsigned short f2bf(float f){
  unsigned int u = __float_as_uint(f);
  u += 0x7fffu + ((u >> 16) & 1u);
  return (unsigned short)(u >> 16);
}

// pack 2 f32 -> 2 bf16 in one instr (RTE, matches f2bf)
__device__ __forceinline__ unsigned int cvtpk(float lo, float hi){
  unsigned int r;
  asm("v_cvt_pk_bf16_f32 %0, %1, %2" : "=v"(r) : "v"(lo), "v"(hi));
  return r;
}

// LDS-visibility sync WITHOUT vmcnt(0) drain (keeps global loads in flight)
__device__ __forceinline__ void block_sync(){
  asm volatile("s_waitcnt lgkmcnt(0)" ::: "memory");
  __builtin_amdgcn_s_barrier();
}

constexpr float SCALE_LOG2E = 0.125f * 1.4426950408889634f; // 1/sqrt(64) * log2(e)

// ---------------- merged prep kernel ----------------
// blocks 0..31: qs + AqT fragments ; 32..287: Cmat+cvec ; 288..543: starts scan
__global__ void k_prep(const float* __restrict__ queries, const float* __restrict__ ipw,
                       const float* __restrict__ ipb, const float* __restrict__ opw,
                       const float* __restrict__ opb, const int* __restrict__ batch,
                       int total, int* __restrict__ starts,
                       unsigned short* __restrict__ AqF,
                       unsigned short* __restrict__ Cmat, float* __restrict__ cvec)
{
  __shared__ __align__(16) float sh[256];
  __shared__ __align__(16) float sh2[256];
  const int t = threadIdx.x, bid = blockIdx.x;

  if (bid < 32){
    const int q = bid;
    sh[t] = queries[q*256 + t];
    __syncthreads();
    const float* wr = ipw + (size_t)t*256;
    float acc = 0.f;
    #pragma unroll 8
    for (int j = 0; j < 256; j += 4){
      float4 wv = *reinterpret_cast<const float4*>(wr + j);
      float4 qv = *reinterpret_cast<const float4*>(&sh[j]);
      acc += wv.x*qv.x + wv.y*qv.y + wv.z*qv.z + wv.w*qv.w;
    }
    sh2[t] = acc + ipb[t];
    __syncthreads();
    #pragma unroll
    for (int h = 0; h < 4; h++){
      const float* wk = ipw + (size_t)(256 + h*64)*256 + t;
      float a2 = 0.f;
      #pragma unroll 8
      for (int d = 0; d < 64; d++) a2 += sh2[h*64 + d] * wk[(size_t)d*256];
      // B-frag layout: AqF[rg=h*2+qh][kb=f>>5][lane=((f>>3)&3)*16 + (q&15)][j=f&7]
      const int dst = ((h*2 + (q>>4))*8 + (t>>5))*512 + (((t>>3)&3)*16 + (q&15))*8 + (t&7);
      AqF[dst] = f2bf(a2 * SCALE_LOG2E);
    }
  } else if (bid < 288){
    const int g = bid - 32;
    sh[t] = opw[(size_t)g*256 + t];
    __syncthreads();
    #pragma unroll
    for (int h = 0; h < 4; h++){
      const float* wv = ipw + (size_t)(512 + h*64)*256 + t;
      float acc = 0.f;
      #pragma unroll 8
      for (int d = 0; d < 64; d++) acc += wv[(size_t)d*256] * sh[h*64 + d];
      Cmat[(size_t)g*1024 + h*256 + t] = f2bf(acc);
    }
    sh2[t] = ipb[512 + t] * sh[t];
    __syncthreads();
    for (int off = 128; off > 0; off >>= 1){
      if (t < off) sh2[t] += sh2[t + off];
      __syncthreads();
    }
    if (t == 0) cvec[g] = sh2[0] + opb[g];
  } else {
    const int sb = bid - 288;
    const int i0 = sb*1024 + t*4;
    if (i0 + 3 < total){
      if (i0 == 0) starts[0] = 0;
      const int4 b4 = *reinterpret_cast<const int4*>(batch + i0);
      if (b4.y != b4.x) starts[b4.y] = i0 + 1;
      if (b4.z != b4.y) starts[b4.z] = i0 + 2;
      if (b4.w != b4.z) starts[b4.w] = i0 + 3;
      if (i0 + 4 < total){
        const int nxt = batch[i0 + 4];
        if (nxt != b4.w) starts[nxt] = i0 + 4;
      } else {
        starts[128] = total;
      }
    }
  }
}

// ---------------- fused attention over raw x (no-max softmax) ----------------
// grid 256 = graph*2 splits, 512 threads (8 waves).
// S phase : wave (a = wave>>1, b = wave&1): rows [a*32,a*32+32), nodes [b*16,b*16+16)
//           of the 32-node chunk; AqT B-frags in REGISTERS; P = exp2(S), no max.
// PV phase: wave w owns f-slice [w*32, w*32+32) for ALL 128 rows.
// One barrier per chunk; xsub[2], xT[3], Plds[2] buffering.

#define LOADC(dst, c_) { \
  const int c0_ = (c_)*32; \
  _Pragma("unroll") \
  for (int n = 0; n < 4; n++){ \
    const int nl_ = c0_ + nb4 + n; \
    float4 v_ = make_float4(0.f,0.f,0.f,0.f); \
    if (nl_ < cnt) v_ = *reinterpret_cast<const float4*>(xg + (size_t)nl_*256 + fq*4); \
    dst[n] = v_; } }

// register 4x4 transpose -> xsub [node][f] (pad 264) AND xT [f][node] (pad 40, XOR swizzle)
#define STAGE(xsP, xtP, src) { \
  float fm[4][4]; \
  _Pragma("unroll") \
  for (int n = 0; n < 4; n++){ \
    fm[n][0]=src[n].x; fm[n][1]=src[n].y; fm[n][2]=src[n].z; fm[n][3]=src[n].w; } \
  _Pragma("unroll") \
  for (int n = 0; n < 4; n++){ \
    uint2 w2; w2.x = cvtpk(fm[n][0], fm[n][1]); w2.y = cvtpk(fm[n][2], fm[n][3]); \
    *reinterpret_cast<uint2*>(&(xsP)[(nb4 + n)*264 + fq*4]) = w2; } \
  _Pragma("unroll") \
  for (int j = 0; j < 4; j++){ \
    const int row_ = fq*4 + j; \
    int byte_ = row_*80 + nb4*2; byte_ ^= ((row_>>2)&7)<<4; \
    uint2 w2; w2.x = cvtpk(fm[0][j], fm[1][j]); w2.y = cvtpk(fm[2][j], fm[3][j]); \
    *reinterpret_cast<uint2*>(reinterpret_cast<char*>(xtP) + byte_) = w2; } }

__global__ __launch_bounds__(512, 2) void k_attn(
    const float* __restrict__ x, const int* __restrict__ starts,
    const unsigned short* __restrict__ AqF,
    float* __restrict__ partO, float* __restrict__ partL)
{
  __shared__ __align__(16) unsigned short xsub[2][32*264];
  __shared__ __align__(16) unsigned short xT  [3][256*40];
  __shared__ __align__(16) unsigned short Plds[2][128*40];
  __shared__ __align__(16) float lred[2][128];

  const int tid = threadIdx.x;
  const int wave = tid >> 6, lane = tid & 63, lg = lane >> 4, li = lane & 15;
  const int nb4 = wave*4, fq = lane;
  const int a = wave >> 1, bsel = wave & 1;
  const int colbase = a*32 + li;            // S cols: colbase (rf=0), colbase+16 (rf=1)
  const int bid = blockIdx.x;
  const int g = bid >> 1, s = bid & 1;
  const int s0 = starts[g], s1 = starts[g+1];
  const int cntg = s1 - s0;
  const int half = (cntg + 1) >> 1;
  const int nstart = s0 + s*half;
  int cnt = cntg - s*half; cnt = cnt < 0 ? 0 : (cnt > half ? half : cnt);
  const int chunks = (cnt + 31) >> 5;
  const float* xg = x + (size_t)nstart*256;

  // AqT B-fragments for rows a*32..a*32+32: row-groups 2a, 2a+1 (registers, constant)
  bf16x8 bfragS[2][8];
  #pragma unroll
  for (int rf = 0; rf < 2; rf++){
    const unsigned short* ap = AqF + (size_t)((a*2 + rf)*8)*512 + lane*8;
    #pragma unroll
    for (int kb = 0; kb < 8; kb++)
      bfragS[rf][kb] = *reinterpret_cast<const bf16x8*>(ap + kb*512);
  }

  f32x4 oacc[16];  // PV accum: [rowtile 8][ftile 2]
  #pragma unroll
  for (int i = 0; i < 16; i++) oacc[i] = f32x4{0.f,0.f,0.f,0.f};
  float lsum0 = 0.f, lsum1 = 0.f;

  // PV bv addresses (fixed per thread)
  int bvb0 = (wave*32 + li)*80 + lg*16;      bvb0 ^= (((wave*32 + li)>>2)&7)<<4;
  int bvb1 = (wave*32 + 16 + li)*80 + lg*16; bvb1 ^= (((wave*32 + 16 + li)>>2)&7)<<4;

  float4 rA[4], rB[4];
  if (chunks > 0){
    LOADC(rA, 0);
    if (chunks > 1) LOADC(rB, 1);
    STAGE(xsub[0], xT[0], rA);
    if (chunks > 2) LOADC(rA, 2);
    block_sync();
  }

  int cur3 = 0;
  for (int c = 0; c < chunks; ++c){
    const int cur2 = c & 1;
    const int nxt3 = (cur3 == 2) ? 0 : cur3 + 1;
    // ---- pre-barrier: stage chunk c+1, refill regs with c+3 ----
    if (c + 1 < chunks){
      unsigned short* xsP = xsub[cur2 ^ 1];
      unsigned short* xtP = xT[nxt3];
      if (c & 1){ STAGE(xsP, xtP, rA); if (c + 3 < chunks) LOADC(rA, c + 3); }
      else      { STAGE(xsP, xtP, rB); if (c + 3 < chunks) LOADC(rB, c + 3); }
    }

    // ---- S-tile: rows a*32..+32, nodes bsel*16..+16 ----
    f32x4 sc0 = f32x4{0.f,0.f,0.f,0.f}, sc1 = f32x4{0.f,0.f,0.f,0.f};
    #pragma unroll
    for (int kb = 0; kb < 8; kb++){
      const bf16x8 af = *reinterpret_cast<const bf16x8*>(&xsub[cur2][(bsel*16 + li)*264 + kb*32 + lg*8]);
      sc0 = MFMA16(af, bfragS[0][kb], sc0);
      sc1 = MFMA16(af, bfragS[1][kb], sc1);
    }

    // ---- P = exp2(S) (no max), accumulate row-sums ----
    const int nodebase = c*32 + bsel*16 + lg*4;
    float p0[4], p1[4];
    #pragma unroll
    for (int r = 0; r < 4; r++){
      const bool v = (nodebase + r) < cnt;
      p0[r] = v ? __builtin_exp2f(sc0[r]) : 0.f;
      p1[r] = v ? __builtin_exp2f(sc1[r]) : 0.f;
      lsum0 += p0[r]; lsum1 += p1[r];
    }
    {
      char* pl = reinterpret_cast<char*>(&Plds[cur2][0]);
      uint2 w0; w0.x = cvtpk(p0[0], p0[1]); w0.y = cvtpk(p0[2], p0[3]);
      uint2 w1; w1.x = cvtpk(p1[0], p1[1]); w1.y = cvtpk(p1[2], p1[3]);
      *reinterpret_cast<uint2*>(pl + colbase*80        + bsel*32 + lg*8) = w0;
      *reinterpret_cast<uint2*>(pl + (colbase+16)*80   + bsel*32 + lg*8) = w1;
    }

    block_sync();   // single barrier per chunk

    // ---- PV: wave owns f-slice [wave*32, wave*32+32) for all 128 rows ----
    const char* xtC = reinterpret_cast<const char*>(xT[cur3]);
    const bf16x8 bv0 = *reinterpret_cast<const bf16x8*>(xtC + bvb0);
    const bf16x8 bv1 = *reinterpret_cast<const bf16x8*>(xtC + bvb1);
    #pragma unroll
    for (int rt = 0; rt < 8; rt++){
      const bf16x8 pa = *reinterpret_cast<const bf16x8*>(&Plds[cur2][(rt*16 + li)*40 + lg*8]);
      oacc[rt*2]   = MFMA16(pa, bv0, oacc[rt*2]);
      oacc[rt*2+1] = MFMA16(pa, bv1, oacc[rt*2+1]);
    }
    cur3 = nxt3;
  }

  // ---- row-sum finalize: reduce over lg, exchange over node-halves ----
  lsum0 += __shfl_xor(lsum0, 16); lsum0 += __shfl_xor(lsum0, 32);
  lsum1 += __shfl_xor(lsum1, 16); lsum1 += __shfl_xor(lsum1, 32);
  if (lane < 16){
    lred[bsel][colbase]      = lsum0;
    lred[bsel][colbase + 16] = lsum1;
  }
  block_sync();
  const int pbase = bid*128;
  if (tid < 128) partL[pbase + tid] = lred[0][tid] + lred[1][tid];

  #pragma unroll
  for (int rt = 0; rt < 8; rt++){
    #pragma unroll
    for (int r = 0; r < 4; r++){
      const size_t orow = (size_t)(pbase + rt*16 + lg*4 + r)*256;
      partO[orow + wave*32 + li]      = oacc[rt*2][r];
      partO[orow + wave*32 + 16 + li] = oacc[rt*2+1][r];
    }
  }
}

// ---------------- combine partials + out-proj GEMM ----------------
__global__ __launch_bounds__(512, 1) void k_out(
    const float* __restrict__ partO, const float* __restrict__ partL,
    const unsigned short* __restrict__ Cmat, const float* __restrict__ cvec,
    float* __restrict__ out)
{
  __shared__ __align__(16) unsigned short plds[16*1024];
  __shared__ float sinv[64];
  const int tid = threadIdx.x;
  const int g = blockIdx.x >> 1, qh = blockIdx.x & 1;
  const int p0 = 2*g, p1 = 2*g + 1;
  if (tid < 64){
    const int h = tid >> 4, qr = tid & 15;
    const int row = h*32 + qh*16 + qr;
    const float L = partL[p0*128 + row] + partL[p1*128 + row];
    sinv[tid] = 1.f / L;
  }
  __syncthreads();
  #pragma unroll
  for (int i = 0; i < 8; i++){
    const int idx = tid + i*512;
    const int qr = idx >> 8;            // 0..15
    const int cg = idx & 255;           // group of 4 cols
    const int h = cg >> 6, f4 = (cg & 63)*4;
    const int row = h*32 + qh*16 + qr;
    const float4 o0 = *reinterpret_cast<const float4*>(&partO[(size_t)(p0*128 + row)*256 + f4]);
    const float4 o1 = *reinterpret_cast<const float4*>(&partO[(size_t)(p1*128 + row)*256 + f4]);
    const float sc = sinv[h*16 + qr];
    uint2 w; w.x = cvtpk((o0.x+o1.x)*sc, (o0.y+o1.y)*sc);
             w.y = cvtpk((o0.z+o1.z)*sc, (o0.w+o1.w)*sc);
    const int col4 = cg*4;
    const int bc = (col4*2) ^ ((qr & 7) << 4);
    *reinterpret_cast<uint2*>(reinterpret_cast<char*>(plds) + qr*2048 + bc) = w;
  }
  __syncthreads();
  const int wave = tid >> 6, lane = tid & 63, lg = lane >> 4, li = lane & 15;
  f32x4 acc0 = {0.f,0.f,0.f,0.f}, acc1 = {0.f,0.f,0.f,0.f};
  const float cv0 = cvec[wave*32 + li], cv1 = cvec[wave*32 + 16 + li];
  const unsigned short* cb0 = Cmat + (size_t)(wave*32 + li)*1024;
  const unsigned short* cb1 = Cmat + (size_t)(wave*32 + 16 + li)*1024;
  #pragma unroll 8
  for (int kb = 0; kb < 32; kb++){
    const int bc = ((kb*32 + lg*8)*2) ^ ((li & 7) << 4);
    const bf16x8 aa = *reinterpret_cast<const bf16x8*>(reinterpret_cast<const char*>(plds) + li*2048 + bc);
    const bf16x8 b0 = *reinterpret_cast<const bf16x8*>(cb0 + kb*32 + lg*8);
    const bf16x8 b1 = *reinterpret_cast<const bf16x8*>(cb1 + kb*32 + lg*8);
    acc0 = MFMA16(aa, b0, acc0);
    acc1 = MFMA16(aa, b1, acc1);
  }
  #pragma unroll
  for (int r = 0; r < 4; r++){
    const int q = lg*4 + r;
    const size_t orow = (size_t)(g*32 + qh*16 + q)*256;
    out[orow + wave*32 + li]      = acc0[r] + cv0;
    out[orow + wave*32 + 16 + li] = acc1[r] + cv1;
  }
}

// ---------------- launch ----------------

extern "C" void kernel_launch(void* const* d_in, const int* in_sizes, int n_in,
                              void* d_out, int out_size, void* d_ws, size_t ws_size,
                              hipStream_t stream)
{
  const float* x       = (const float*)d_in[0];
  const int*   batch   = (const int*)d_in[1];
  const float* queries = (const float*)d_in[2];
  const float* ipw     = (const float*)d_in[3];
  const float* ipb     = (const float*)d_in[4];
  const float* opw     = (const float*)d_in[5];
  const float* opb     = (const float*)d_in[6];
  float* out = (float*)d_out;
  const int total = in_sizes[1];

  char* w = (char*)d_ws;
  int*            starts = (int*)(w);
  unsigned short* AqF    = (unsigned short*)(w + 36*1024);
  unsigned short* Cmat   = (unsigned short*)(w + 102*1024);
  float*          cvec   = (float*)(w + 616*1024);
  float*          partO  = (float*)(w + (size_t)1024*1024);
  float*          partL  = (float*)(w + (size_t)1024*1024 + (size_t)256*128*256*4);

  k_prep<<<544, 256, 0, stream>>>(queries, ipw, ipb, opw, opb, batch, total,
                                  starts, AqF, Cmat, cvec);
  k_attn<<<256, 512, 0, stream>>>(x, starts, AqF, partO, partL);
  k_out<<<256, 512, 0, stream>>>(partO, partL, Cmat, cvec, out);
}